// Round 1
// baseline (267.173 us; speedup 1.0000x reference)
//
#include <hip/hip_runtime.h>
#include <hip/hip_bf16.h>
#include <stdint.h>

#define HWN 50176   // 224*224
#define NM  1000
#define FD  128
#define SPLITK 49
#define KSTEPS 32
#define BK 32

typedef __attribute__((ext_vector_type(8))) short short8;
typedef __attribute__((ext_vector_type(4))) float f32x4;
typedef __attribute__((ext_vector_type(4))) float float4v;

__device__ __forceinline__ unsigned short f2bf(float x) {
    union { float f; unsigned u; } v; v.f = x;
    unsigned r = v.u + 0x7FFFu + ((v.u >> 16) & 1u);
    return (unsigned short)(r >> 16);
}
__device__ __forceinline__ float bf2f(unsigned short h) {
    union { float f; unsigned u; } v; v.u = ((unsigned)h) << 16;
    return v.f;
}

// Stage 1: A[hw,f] = sum_c img[c,hw]*W[c,hw,f], stored transposed bf16: AbT[f][hw]
__global__ __launch_bounds__(256) void k_encode(const float* __restrict__ img,
                                                const float* __restrict__ Wt,
                                                unsigned short* __restrict__ AbT)
{
    const int t = threadIdx.x;
    const int f = t & 127;
    const int base = blockIdx.x * 64 + (t >> 7) * 32;
    unsigned short ov[32];
#pragma unroll
    for (int i = 0; i < 32; ++i) {
        const int hw = base + i;
        float a =      img[hw]           * Wt[(size_t)hw * FD + f];
        a = fmaf(img[HWN + hw],   Wt[((size_t)HWN + hw) * FD + f], a);
        a = fmaf(img[2 * HWN + hw], Wt[((size_t)2 * HWN + hw) * FD + f], a);
        ov[i] = f2bf(a);
    }
    unsigned short* dst = AbT + (size_t)f * HWN + base;
#pragma unroll
    for (int i = 0; i < 4; ++i)
        *reinterpret_cast<short8*>(dst + i * 8) = *reinterpret_cast<const short8*>(ov + i * 8);
}

// Stage 2: rep0[f] = sum_hw A[hw,f]  (one block per f, reads AbT row)
__global__ __launch_bounds__(256) void k_rep0(const unsigned short* __restrict__ AbT,
                                              float* __restrict__ rep0)
{
    const int f = blockIdx.x;
    const unsigned short* row = AbT + (size_t)f * HWN;
    float s = 0.f;
    for (int i = threadIdx.x; i < HWN; i += 256) s += bf2f(row[i]);
    __shared__ float red[256];
    red[threadIdx.x] = s;
    __syncthreads();
    for (int o = 128; o > 0; o >>= 1) {
        if (threadIdx.x < o) red[threadIdx.x] += red[threadIdx.x + o];
        __syncthreads();
    }
    if (threadIdx.x == 0) rep0[f] = red[0];
}

// Stage 3: split-K GEMM  partial[split][n][f] += masks[n, kchunk] * A[kchunk, f]
// blockIdx.x = mtile (0..15, 64 rows each), blockIdx.y = split (0..48, K-chunk of 1024)
__global__ __launch_bounds__(256) void k_gemm(const float* __restrict__ masks,
                                              const unsigned short* __restrict__ AbT,
                                              float* __restrict__ partial)
{
    __shared__ __align__(16) unsigned short As[64][40];   // +8 pad: bank spread
    __shared__ __align__(16) unsigned short Bs[128][40];

    const int t = threadIdx.x;
    const int mtile = blockIdx.x;
    const int split = blockIdx.y;
    const int n0 = mtile * 64;
    const int kbase = split * (KSTEPS * BK);

    // masks-tile loader role: 64 rows x 32 cols fp32, 8 per thread
    const int ar = t >> 2;
    const int ac = (t & 3) * 8;
    const int an = n0 + ar;
    const bool avalid = (an < NM);
    const float* aptr = masks + (size_t)(avalid ? an : 0) * HWN;

    // B-tile loader role: 128 rows x 32 cols bf16, 16 per thread
    const int bfr = t >> 1;
    const int bk = (t & 1) * 16;
    const unsigned short* bptr = AbT + (size_t)bfr * HWN;

    const int lane = t & 63;
    const int wv = t >> 6;          // wave id 0..3 -> M sub-rows
    const int lrow = lane & 15;
    const int lk = (lane >> 4) * 8;

    f32x4 acc[8];
#pragma unroll
    for (int i = 0; i < 8; ++i) acc[i] = f32x4{0.f, 0.f, 0.f, 0.f};

    for (int ks = 0; ks < KSTEPS; ++ks) {
        const int k0 = kbase + ks * BK;
        float4v a0 = {0.f,0.f,0.f,0.f}, a1 = {0.f,0.f,0.f,0.f};
        if (avalid) {
            a0 = *reinterpret_cast<const float4v*>(aptr + k0 + ac);
            a1 = *reinterpret_cast<const float4v*>(aptr + k0 + ac + 4);
        }
        short8 b0 = *reinterpret_cast<const short8*>(bptr + k0 + bk);
        short8 b1 = *reinterpret_cast<const short8*>(bptr + k0 + bk + 8);

        short8 apk;
        apk[0] = (short)f2bf(a0[0]); apk[1] = (short)f2bf(a0[1]);
        apk[2] = (short)f2bf(a0[2]); apk[3] = (short)f2bf(a0[3]);
        apk[4] = (short)f2bf(a1[0]); apk[5] = (short)f2bf(a1[1]);
        apk[6] = (short)f2bf(a1[2]); apk[7] = (short)f2bf(a1[3]);

        __syncthreads();   // previous iteration's fragment reads complete
        *reinterpret_cast<short8*>(&As[ar][ac]) = apk;
        *reinterpret_cast<short8*>(&Bs[bfr][bk]) = b0;
        *reinterpret_cast<short8*>(&Bs[bfr][bk + 8]) = b1;
        __syncthreads();

        const short8 af = *reinterpret_cast<const short8*>(&As[wv * 16 + lrow][lk]);
#pragma unroll
        for (int ft = 0; ft < 8; ++ft) {
            const short8 bfv = *reinterpret_cast<const short8*>(&Bs[ft * 16 + lrow][lk]);
            acc[ft] = __builtin_amdgcn_mfma_f32_16x16x32_bf16(af, bfv, acc[ft], 0, 0, 0);
        }
    }

    // epilogue: C row = n0 + wv*16 + (lane>>4)*4 + r, col = ft*16 + (lane&15)
    const int crow0 = n0 + wv * 16 + ((lane >> 4) << 2);
    float* pb = partial + ((size_t)split * 1024 + crow0) * FD + lrow;
#pragma unroll
    for (int ft = 0; ft < 8; ++ft) {
#pragma unroll
        for (int r = 0; r < 4; ++r)
            pb[(size_t)r * FD + ft * 16] = acc[ft][r];
    }
}

// Stage 4: reduce split-K partials, cosine similarity vs rep0
__global__ __launch_bounds__(128) void k_sims(const float* __restrict__ partial,
                                              const float* __restrict__ rep0,
                                              float* __restrict__ sims)
{
    const int n = blockIdx.x;
    const int f = threadIdx.x;
    float r = 0.f;
    for (int s = 0; s < SPLITK; ++s)
        r += partial[((size_t)s * 1024 + n) * FD + f];
    const float r0 = rep0[f];
    __shared__ float red0[128], red1[128], red2[128];
    red0[f] = r * r0;
    red1[f] = r * r;
    red2[f] = r0 * r0;
    __syncthreads();
    for (int o = 64; o > 0; o >>= 1) {
        if (f < o) {
            red0[f] += red0[f + o];
            red1[f] += red1[f + o];
            red2[f] += red2[f + o];
        }
        __syncthreads();
    }
    if (f == 0) {
        const float dot = red0[0];
        const float nr = fmaxf(sqrtf(red1[0]), 1e-8f);
        const float nz = fmaxf(sqrtf(red2[0]), 1e-8f);
        sims[n] = dot / (nr * nz);
    }
}

// Stage 5: per-pixel sequential weighted mean/variance scan over 1000 masks
__global__ __launch_bounds__(256) void k_scan(const float* __restrict__ masks,
                                              const float* __restrict__ sims,
                                              float* __restrict__ out)
{
    __shared__ float ss[NM];
    for (int i = threadIdx.x; i < NM; i += 256) ss[i] = sims[i];
    __syncthreads();
    const int pix = blockIdx.x * 256 + threadIdx.x;
    const float* mp = masks + pix;
    float imp = 0.f, unc = 0.f, sow = 1e-10f;
#pragma unroll 4
    for (int n = 0; n < NM; ++n) {
        const float m = mp[(size_t)n * HWN];
        const float s = ss[n];
        sow += m;
        const float prev = imp;
        imp += m * (s - imp) / sow;
        unc += (s - imp) * (s - prev) * m;
    }
    out[pix] = imp;
    out[HWN + pix] = unc;
    out[2 * HWN + pix] = sow;
}

extern "C" void kernel_launch(void* const* d_in, const int* in_sizes, int n_in,
                              void* d_out, int out_size, void* d_ws, size_t ws_size,
                              hipStream_t stream) {
    const float* img   = (const float*)d_in[0];   // [1,3,224,224]
    const float* masks = (const float*)d_in[1];   // [1000,224,224]
    const float* Wt    = (const float*)d_in[2];   // [3,224,224,128]
    float* out = (float*)d_out;                   // [3,224,224]

    char* ws = (char*)d_ws;
    unsigned short* AbT = (unsigned short*)ws;                       // 12,845,056 B
    float* partial = (float*)(ws + 12845056);                        // 25,690,112 B
    float* rep0    = (float*)(ws + 12845056 + 25690112);             // 512 B
    float* sims    = (float*)(ws + 12845056 + 25690112 + 512);       // 4,000 B

    hipLaunchKernelGGL(k_encode, dim3(784), dim3(256), 0, stream, img, Wt, AbT);
    hipLaunchKernelGGL(k_rep0,   dim3(128), dim3(256), 0, stream, AbT, rep0);
    hipLaunchKernelGGL(k_gemm,   dim3(16, 49), dim3(256), 0, stream, masks, AbT, partial);
    hipLaunchKernelGGL(k_sims,   dim3(NM), dim3(128), 0, stream, partial, rep0, sims);
    hipLaunchKernelGGL(k_scan,   dim3(196), dim3(256), 0, stream, masks, sims, out);
}

// Round 2
// 126.624 us; speedup vs baseline: 2.1100x; 2.1100x over previous
//
#include <hip/hip_runtime.h>
#include <stdint.h>

#define HWN 50176   // 224*224
#define NM  1000
#define FD  128
#define NSPLIT 49
#define KSTEPS 32
#define NSCAN 8
#define NPB 125     // 1000 / 8

typedef __attribute__((ext_vector_type(8))) short short8;
typedef __attribute__((ext_vector_type(4))) float f32x4;

__device__ __forceinline__ unsigned short f2bf(float x) {
    union { float f; unsigned u; } v; v.f = x;
    unsigned r = v.u + 0x7FFFu + ((v.u >> 16) & 1u);
    return (unsigned short)(r >> 16);
}

#define AS1(p) ((const __attribute__((address_space(1))) unsigned int*)(p))
#define AS3(p) ((__attribute__((address_space(3))) unsigned int*)(p))

// Stage 1: A[hw,f] = sum_c img*W, written as swizzled bf16 k-tiles:
// tile kt (k in [kt*32, kt*32+32)), 8192B: row f (64B), 16B chunk j stored at
// slot (j ^ (f&3)).  Also fp32 per-block rep0 partials.
__global__ __launch_bounds__(256) void k_encode(const float* __restrict__ img,
                                                const float* __restrict__ Wt,
                                                unsigned short* __restrict__ Bpack,
                                                float* __restrict__ rep0part)
{
    const int t = threadIdx.x;
    const int f = t & 127;
    const int kt = blockIdx.x * 2 + (t >> 7);
    const int hw0 = kt * 32;
    float vals[32];
    float rsum = 0.f;
#pragma unroll
    for (int e = 0; e < 32; ++e) {
        const int hw = hw0 + e;
        float a = img[hw] * Wt[(size_t)hw * FD + f];
        a = fmaf(img[HWN + hw],     Wt[(size_t)(HWN + hw) * FD + f], a);
        a = fmaf(img[2 * HWN + hw], Wt[(size_t)(2 * HWN + hw) * FD + f], a);
        vals[e] = a;
        rsum += a;
    }
    char* tile = (char*)Bpack + (size_t)kt * 8192 + f * 64;
#pragma unroll
    for (int j = 0; j < 4; ++j) {
        short8 pk;
#pragma unroll
        for (int e = 0; e < 8; ++e) pk[e] = (short)f2bf(vals[j * 8 + e]);
        *reinterpret_cast<short8*>(tile + ((j ^ (f & 3)) << 4)) = pk;
    }
    __shared__ float red[256];
    red[t] = rsum;
    __syncthreads();
    if (t < 128) rep0part[(size_t)blockIdx.x * 128 + f] = red[t] + red[t + 128];
}

// Stage 2: rep0[f] = sum of 784 partials
__global__ __launch_bounds__(256) void k_rep0red(const float* __restrict__ rep0part,
                                                 float* __restrict__ rep0)
{
    const int f = blockIdx.x;
    float s = 0.f;
    for (int b = threadIdx.x; b < 784; b += 256) s += rep0part[(size_t)b * 128 + f];
    __shared__ float red[256];
    red[threadIdx.x] = s;
    __syncthreads();
    for (int o = 128; o > 0; o >>= 1) {
        if (threadIdx.x < o) red[threadIdx.x] += red[threadIdx.x + o];
        __syncthreads();
    }
    if (threadIdx.x == 0) rep0[f] = red[0];
}

// Stage 3: split-K GEMM, 128-row M-tile, 8 waves, double-buffered B via
// global_load_lds (swizzled pack), A (masks) global->reg->bf16.
__global__ __launch_bounds__(512, 4) void k_gemm(const float* __restrict__ masks,
                                                 const unsigned short* __restrict__ Bpack,
                                                 float* __restrict__ partial)
{
    __shared__ __align__(16) unsigned short Bs[2][4096];   // 2 x 8192 B

    const int t = threadIdx.x;
    const int wv = t >> 6, lane = t & 63;
    const int lrow = lane & 15, lslot = lane >> 4;
    const int mtile = blockIdx.x, split = blockIdx.y;

    int row = mtile * 128 + wv * 16 + lrow;
    if (row >= NM) row = NM - 1;                  // clamp: rows >=1000 never read back
    const float* aptr = masks + (size_t)row * HWN + split * 1024 + lslot * 8;
    const char* bsrc = (const char*)Bpack + (size_t)(split * KSTEPS) * 8192 + t * 16;
    char* dst0 = (char*)&Bs[0][0] + t * 16;
    char* dst1 = (char*)&Bs[1][0] + t * 16;
    const int rdoff = lrow * 64 + ((lslot ^ (lrow & 3)) << 4);

    f32x4 acc[8];
#pragma unroll
    for (int i = 0; i < 8; ++i) acc[i] = f32x4{0.f, 0.f, 0.f, 0.f};

    // prologue: B(0) DMA + A(0) reg loads
    __builtin_amdgcn_global_load_lds(AS1(bsrc), AS3(dst0), 16, 0, 0);
    f32x4 a0 = *reinterpret_cast<const f32x4*>(aptr);
    f32x4 a1 = *reinterpret_cast<const f32x4*>(aptr + 4);

    for (int ks = 0; ks < KSTEPS; ++ks) {
        const int cur = ks & 1;
        __syncthreads();   // compiler drains vmcnt/lgkm: B(ks)+A(ks) landed, prev reads done
        if (ks + 1 < KSTEPS)
            __builtin_amdgcn_global_load_lds(AS1(bsrc + (size_t)(ks + 1) * 8192),
                                             AS3(cur ? dst0 : dst1), 16, 0, 0);
        const int kn = (ks + 1 < KSTEPS) ? (ks + 1) : ks;
        f32x4 na0 = *reinterpret_cast<const f32x4*>(aptr + kn * 32);
        f32x4 na1 = *reinterpret_cast<const f32x4*>(aptr + kn * 32 + 4);

        short8 apk;
        apk[0] = (short)f2bf(a0[0]); apk[1] = (short)f2bf(a0[1]);
        apk[2] = (short)f2bf(a0[2]); apk[3] = (short)f2bf(a0[3]);
        apk[4] = (short)f2bf(a1[0]); apk[5] = (short)f2bf(a1[1]);
        apk[6] = (short)f2bf(a1[2]); apk[7] = (short)f2bf(a1[3]);

        const char* bbase = (const char*)&Bs[cur][0] + rdoff;
#pragma unroll
        for (int ft = 0; ft < 8; ++ft) {
            short8 bfv = *reinterpret_cast<const short8*>(bbase + ft * 1024);
            acc[ft] = __builtin_amdgcn_mfma_f32_16x16x32_bf16(apk, bfv, acc[ft], 0, 0, 0);
        }
        a0 = na0; a1 = na1;
    }

    const int crow = mtile * 128 + wv * 16 + (lslot << 2);
    float* pb = partial + ((size_t)split * 1024 + crow) * FD + lrow;
#pragma unroll
    for (int ft = 0; ft < 8; ++ft)
#pragma unroll
        for (int r = 0; r < 4; ++r)
            pb[(size_t)r * FD + ft * 16] = acc[ft][r];
}

// Stage 4: reduce split-K partials, cosine similarity vs rep0
__global__ __launch_bounds__(128) void k_sims(const float* __restrict__ partial,
                                              const float* __restrict__ rep0,
                                              float* __restrict__ sims)
{
    const int n = blockIdx.x;
    const int f = threadIdx.x;
    float r = 0.f;
    for (int s = 0; s < NSPLIT; ++s)
        r += partial[((size_t)s * 1024 + n) * FD + f];
    const float r0 = rep0[f];
    __shared__ float red0[128], red1[128], red2[128];
    red0[f] = r * r0;
    red1[f] = r * r;
    red2[f] = r0 * r0;
    __syncthreads();
    for (int o = 64; o > 0; o >>= 1) {
        if (f < o) {
            red0[f] += red0[f + o];
            red1[f] += red1[f + o];
            red2[f] += red2[f + o];
        }
        __syncthreads();
    }
    if (f == 0) {
        const float nr = fmaxf(sqrtf(red1[0]), 1e-8f);
        const float nz = fmaxf(sqrtf(red2[0]), 1e-8f);
        sims[n] = red0[0] / (nr * nz);
    }
}

// Stage 5a: per-pixel weighted sums S0,S1,S2 over an n-chunk (closed-form scan)
__global__ __launch_bounds__(256) void k_colsums(const float* __restrict__ masks,
                                                 const float* __restrict__ sims,
                                                 float* __restrict__ Spart)
{
    __shared__ float s1v[NPB], s2v[NPB];
    const int t = threadIdx.x;
    const int split = blockIdx.y;
    if (t < NPB) {
        const float s = sims[split * NPB + t];
        s1v[t] = s;
        s2v[t] = s * s;
    }
    __syncthreads();
    const int pix = blockIdx.x * 256 + t;
    const float* mp = masks + (size_t)split * NPB * HWN + pix;
    float s0 = 0.f, s1 = 0.f, s2 = 0.f;
#pragma unroll 5
    for (int i = 0; i < NPB; ++i) {
        const float m = mp[(size_t)i * HWN];
        s0 += m;
        s1 = fmaf(m, s1v[i], s1);
        s2 = fmaf(m, s2v[i], s2);
    }
    float* sp = Spart + (size_t)split * 3 * HWN + pix;
    sp[0] = s0;
    sp[HWN] = s1;
    sp[2 * HWN] = s2;
}

// Stage 5b: combine splits, closed-form imp/unc/sow
__global__ __launch_bounds__(256) void k_final(const float* __restrict__ Spart,
                                               float* __restrict__ out)
{
    const int pix = blockIdx.x * 256 + threadIdx.x;
    float s0 = 0.f, s1 = 0.f, s2 = 0.f;
#pragma unroll
    for (int sp = 0; sp < NSCAN; ++sp) {
        const float* p = Spart + (size_t)sp * 3 * HWN + pix;
        s0 += p[0];
        s1 += p[HWN];
        s2 += p[2 * HWN];
    }
    const float sow = 1e-10f + s0;
    const float imp = s1 / sow;
    const float unc = fmaf(-imp, s1, s2);   // S2 - S1^2/sow
    out[pix] = imp;
    out[HWN + pix] = unc;
    out[2 * HWN + pix] = sow;
}

extern "C" void kernel_launch(void* const* d_in, const int* in_sizes, int n_in,
                              void* d_out, int out_size, void* d_ws, size_t ws_size,
                              hipStream_t stream) {
    const float* img   = (const float*)d_in[0];
    const float* masks = (const float*)d_in[1];
    const float* Wt    = (const float*)d_in[2];
    float* out = (float*)d_out;

    char* ws = (char*)d_ws;
    unsigned short* Bpack = (unsigned short*)ws;                 // 12,845,056 B
    float* partial  = (float*)(ws + 12845056);                   // 25,690,112 B
    float* rep0part = partial;                                   // alias: consumed before gemm writes
    float* rep0     = (float*)(ws + 38535168);                   // 512 B
    float* sims     = (float*)(ws + 38535680);                   // 4,000 B
    float* Spart    = (float*)ws;                                // alias Bpack: gemm done by then

    hipLaunchKernelGGL(k_encode,  dim3(784), dim3(256), 0, stream, img, Wt, Bpack, rep0part);
    hipLaunchKernelGGL(k_rep0red, dim3(128), dim3(256), 0, stream, rep0part, rep0);
    hipLaunchKernelGGL(k_gemm,    dim3(8, NSPLIT), dim3(512), 0, stream, masks, Bpack, partial);
    hipLaunchKernelGGL(k_sims,    dim3(NM), dim3(128), 0, stream, partial, rep0, sims);
    hipLaunchKernelGGL(k_colsums, dim3(196, NSCAN), dim3(256), 0, stream, masks, sims, Spart);
    hipLaunchKernelGGL(k_final,   dim3(196), dim3(256), 0, stream, Spart, out);
}